// Round 5
// baseline (626.099 us; speedup 1.0000x reference)
//
#include <hip/hip_runtime.h>

#define N_NODES 100000
#define D 128
#define N_EDGES 640000
#define TOT_EDGES (3 * N_EDGES)   // 1,920,000

#define NB   1024                 // buckets (node ranges)
#define NPB  98                   // nodes per bucket (1024*98 >= 100000)
#define BCAP 2304                 // record cap per bucket (mean 1875, ~+10 sigma; 9*256)
#define RPT  9                    // records per thread in binB (BCAP/256)
#define OVF_CAP 16384
#define EPB  2560                 // edges per binA block (divides N_EDGES: 250 blocks/set)
#define BINA_BLOCKS (TOT_EDGES / EPB)   // 750
#define BLK_PER_SET (N_EDGES / EPB)     // 250
#define EPT  (EPB / 256)                // 10 edges per thread
#define NKEY 512                  // pow2 >= NPB*4 (local*4+set sort key space)

#define NSL  8                    // column slices (one per XCD)
#define SLW  16                   // output cols per slice
#define SLB  36                   // bytes per node per slice: 9 dwords = 18 bf16 cols
#define SLICE_BYTES ((size_t)N_NODES * SLB)   // 3,600,000 -> fits 4MiB XCD L2

#define SCAST_BLOCKS (N_NODES / 4)            // 25000 (wave per node, 4 waves/block)
#define NPG  16                               // nodes per gather block (per slice)
#define GATHER_BLOCKS ((N_NODES / NPG) * NSL) // 6250*8 = 50000

// ---------------- fast-path ws layout (bytes); total 48,802,112 ------------
#define WS_OVFCNT 0
#define WS_BCUR   64                         // int, stride 16 ints (64B/bucket) x1024
#define WS_OVF    65600                      // int4[OVF_CAP], 256 KB
#define WS_TMP    327744                     // int2[NB*BCAP], 18.87 MB (sorted in place)
#define WS_OFFS   19202112                   // int[N_NODES] abs index into tmp
#define WS_CNTS   19602112                   // int[N_NODES]
#define WS_XB3    20002112                   // char[8 * 100000 * 36], 28.8 MB
#define WS_TOTAL_FAST 48802112

__device__ __forceinline__ void load_r(const float* z0, const float* z1,
                                       const float* z2, const float* z3,
                                       float& r0, float& r1, float& r2, float& r3) {
    r0 = fmaxf(z0[0], 0.0f);
    r1 = fmaxf(z1[0], 0.0f);
    r2 = fmaxf(z2[0], 0.0f);
    r3 = fmaxf(z3[0], 0.0f);
    float inv = 1.0f / (r0 + r1 + r2 + r3 + 1e-6f);
    r0 *= inv; r1 *= inv; r2 *= inv; r3 *= inv;
}

__device__ __forceinline__ unsigned short bf16rn(float f) {
    unsigned int u = __float_as_uint(f);
    u += 0x7FFFu + ((u >> 16) & 1u);   // round to nearest even
    return (unsigned short)(u >> 16);
}

// ---------------------------------------------------------------------------
// prep: merged slice-cast (x -> xb3 slice-major bf16, 18 cols/slice with
// 2-col halo for the roll) + binA (LDS-aggregated edge binning into 1024
// node-range buckets). tmp rec: x = dst(17)|set<<17(2)|local<<19(7), y = scale.
// ---------------------------------------------------------------------------
__global__ __launch_bounds__(256) void prep_kernel(
        const float* __restrict__ x, char* __restrict__ xb3,
        const int* __restrict__ ei1, const float* __restrict__ w1,
        const int* __restrict__ ei2, const float* __restrict__ w2,
        const int* __restrict__ ei3, const float* __restrict__ w3,
        const float* __restrict__ z0, const float* __restrict__ z1,
        const float* __restrict__ z2, const float* __restrict__ z3,
        int* __restrict__ bcur, int* __restrict__ ovf_count,
        int4* __restrict__ ovf, int2* __restrict__ tmp) {
    if (blockIdx.x >= BINA_BLOCKS) {
        // ---- slice-cast branch: wave per node ----
        int c    = blockIdx.x - BINA_BLOCKS;
        int w    = threadIdx.x >> 6;
        int lane = threadIdx.x & 63;
        int node = c * 4 + w;                 // < 100000 by construction
        float2 xv = ((const float2*)(x + (size_t)node * D))[lane];
        unsigned int vd = ((unsigned int)bf16rn(xv.y) << 16) | (unsigned int)bf16rn(xv.x);
        // row dword d (cols 2d,2d+1) -> slice s1 = d>>3 at pos (d&7)+1;
        // dwords with d&7==7 are also the halo (pos 0) of slice s1+1.
        int d  = lane;
        int s1 = d >> 3;
        *(unsigned int*)(xb3 + (size_t)s1 * SLICE_BYTES + (size_t)node * SLB
                         + (size_t)(((d & 7) + 1) << 2)) = vd;
        if ((d & 7) == 7) {
            int s2 = (s1 + 1) & 7;
            *(unsigned int*)(xb3 + (size_t)s2 * SLICE_BYTES + (size_t)node * SLB) = vd;
        }
        return;
    }
    // ---- binA branch (whole block within one edge set) ----
    __shared__ int hist[NB];
    __shared__ int base[NB];
    int t = threadIdx.x;
    for (int i = t; i < NB; i += 256) hist[i] = 0;
    __syncthreads();

    float r0, r1, r2, r3;
    load_r(z0, z1, z2, z3, r0, r1, r2, r3);

    int set = blockIdx.x / BLK_PER_SET;
    int e0  = (blockIdx.x - set * BLK_PER_SET) * EPB;
    const int* ei;  const float* w;  float rk;
    if      (set == 0) { ei = ei1; w = w1; rk = r1; }
    else if (set == 1) { ei = ei2; w = w2; rk = r2; }
    else               { ei = ei3; w = w3; rk = r3; }

    int rank[EPT];
    int bkt[EPT];
    int rxv[EPT];
    float scv[EPT];

#pragma unroll
    for (int k = 0; k < EPT; ++k) {
        int idx = e0 + t + k * 256;
        int src = ei[idx];
        int dst = ei[N_EDGES + idx];
        int b = src / NPB;
        int local = src - b * NPB;
        bkt[k]  = b;
        rxv[k]  = dst | (set << 17) | (local << 19);
        scv[k]  = rk * w[idx];
        rank[k] = atomicAdd(&hist[b], 1);
    }
    __syncthreads();

    for (int i = t; i < NB; i += 256) {
        int h = hist[i];
        base[i] = h ? atomicAdd(&bcur[i * 16], h) : 0;
    }
    __syncthreads();

#pragma unroll
    for (int k = 0; k < EPT; ++k) {
        int b = bkt[k];
        int pos = base[b] + rank[k];
        if (pos < BCAP) {
            tmp[(size_t)b * BCAP + pos] = make_int2(rxv[k], __float_as_int(scv[k]));
        } else {
            int o = atomicAdd(ovf_count, 1);
            int src = b * NPB + ((rxv[k] >> 19) & 0x7F);
            if (o < OVF_CAP) ovf[o] = make_int4(src, rxv[k] & 0x7FFFF,
                                                __float_as_int(scv[k]), 0);
        }
    }
}

// ---------------------------------------------------------------------------
// binB: per-bucket counting sort by key = local*4+set, IN PLACE in tmp
// (records staged through registers; barriers separate read/scatter).
// Emits per-node CSR (offs = absolute index into tmp, cnts = degree).
// ---------------------------------------------------------------------------
__global__ __launch_bounds__(256) void binB_kernel(
        const int* __restrict__ bcur, int2* __restrict__ tmp,
        int* __restrict__ offs, int* __restrict__ cnts) {
    __shared__ int dH[NKEY];
    __shared__ int ts[256];
    __shared__ int cur[NKEY];
    __shared__ int nb[NPB + 1];
    int b = blockIdx.x;
    int t = threadIdx.x;
    int n = bcur[b * 16];
    if (n > BCAP) n = BCAP;

    int mrx[RPT], mry[RPT];
#pragma unroll
    for (int k = 0; k < RPT; ++k) {
        int i = t + k * 256;
        if (i < n) { int2 r = tmp[(size_t)b * BCAP + i]; mrx[k] = r.x; mry[k] = r.y; }
        else       { mrx[k] = -1; mry[k] = 0; }
    }

    dH[t] = 0; dH[t + 256] = 0;
    __syncthreads();
#pragma unroll
    for (int k = 0; k < RPT; ++k) {
        if (mrx[k] != -1) {
            int key = (((mrx[k] >> 19) & 0x7F) << 2) | ((mrx[k] >> 17) & 3);
            atomicAdd(&dH[key], 1);
        }
    }
    __syncthreads();

    int k0 = dH[2 * t], k1 = dH[2 * t + 1];
    int tot = k0 + k1;
    ts[t] = tot;
    __syncthreads();
    for (int off = 1; off < 256; off <<= 1) {
        int v = (t >= off) ? ts[t - off] : 0;
        __syncthreads();
        ts[t] += v;
        __syncthreads();
    }
    int tb = ts[t] - tot;
    cur[2 * t]     = tb;
    cur[2 * t + 1] = tb + k0;
    __syncthreads();

    if (t <= NPB) nb[t] = (t < NPB) ? cur[t << 2] : n;
    __syncthreads();

#pragma unroll
    for (int k = 0; k < RPT; ++k) {
        if (mrx[k] != -1) {
            int key = (((mrx[k] >> 19) & 0x7F) << 2) | ((mrx[k] >> 17) & 3);
            int pos = atomicAdd(&cur[key], 1);
            tmp[(size_t)b * BCAP + pos] = make_int2(mrx[k], mry[k]);
        }
    }

    if (t < NPB) {
        int node = b * NPB + t;
        if (node < N_NODES) {
            offs[node] = b * BCAP + nb[t];
            cnts[node] = nb[t + 1] - nb[t];
        }
    }
}

// ---------------------------------------------------------------------------
// gslice: XCD-sliced gather. slice = blockIdx % 8 (HW round-robins blocks
// over the 8 XCDs, so each XCD sees ONE 3.6MB xb3 slice -> L2-resident).
// Wave: 8 records x 8 lanes; lane l reads dword l of the 9-dword record
// slice (+ broadcast dword 8); input-space accumulators, 3-shfl rotation
// fix-up + xor-tree reduce per node. Record stream read nontemporal.
// ---------------------------------------------------------------------------
__global__ __launch_bounds__(256) void gslice_kernel(
        const float* __restrict__ x, const char* __restrict__ xb3,
        const int* __restrict__ offs, const int* __restrict__ cnts,
        const int2* __restrict__ tmp,
        const float* __restrict__ z0, const float* __restrict__ z1,
        const float* __restrict__ z2, const float* __restrict__ z3,
        float* __restrict__ out) {
    int s  = blockIdx.x & 7;
    int ng = blockIdx.x >> 3;
    int w    = threadIdx.x >> 6;
    int lane = threadIdx.x & 63;
    int g = lane >> 3;
    int l = lane & 7;
    const char* xs = xb3 + (size_t)s * SLICE_BYTES;
    int c0 = s * SLW;

    float r0, r1, r2, r3;
    load_r(z0, z1, z2, z3, r0, r1, r2, r3);

    unsigned int loff = (unsigned int)(l << 2);

    for (int ni = 0; ni < NPG / 4; ++ni) {
        int node = ng * NPG + w + ni * 4;     // < N_NODES (6250*16 = 100000)
        int beg = offs[node];
        int cnt = cnts[node];

        float A0x = 0.f, A0y = 0.f, A1x = 0.f, A1y = 0.f, A2x = 0.f, A2y = 0.f;
        float X0 = 0.f, X1 = 0.f, X2 = 0.f;

        for (int j = 0; j < cnt; j += 8) {
            int q = j + g;
            int ii = beg + ((q < cnt) ? q : cnt - 1);
            const int* rp = (const int*)(tmp + ii);
            int rx = __builtin_nontemporal_load(rp);
            int ry = __builtin_nontemporal_load(rp + 1);
            float sc = (q < cnt) ? __int_as_float(ry) : 0.f;
            int dst = rx & 0x1FFFF;
            int sh  = (rx >> 17) & 3;
            unsigned int boff = (unsigned int)dst * 36u;
            unsigned int u  = *(const unsigned int*)(xs + boff + loff);
            unsigned int u8 = *(const unsigned int*)(xs + boff + 32u);
            float lo  = __uint_as_float(u << 16);
            float hi  = __uint_as_float(u & 0xFFFF0000u);
            float lo8 = __uint_as_float(u8 << 16);
            float hi8 = __uint_as_float(u8 & 0xFFFF0000u);
            float m0 = (sh == 0) ? sc : 0.f;
            float m1 = (sh == 1) ? sc : 0.f;
            float m2 = (sh == 2) ? sc : 0.f;
            A0x += m0 * lo;  A0y += m0 * hi;
            A1x += m1 * lo;  A1y += m1 * hi;
            A2x += m2 * lo;  A2y += m2 * hi;
            X0  += m0 * lo8; X1  += m0 * hi8; X2 += m1 * lo8;
        }

        // rotation fix-up: lane d takes A0/A1 from lane d+1 (lane 0's slot
        // carries the dword-8 extras so lane 7 wraps onto them).
        float M0 = (l == 0) ? X0 : A0x;
        float M1 = (l == 0) ? X1 : A0y;
        float M2 = (l == 0) ? X2 : A1x;
        int sl = (lane & 56) | ((l + 1) & 7);
        float va = __shfl(M0, sl);
        float vb = __shfl(M1, sl);
        float vc = __shfl(M2, sl);
        float oe = va + A1y + A2x;
        float oo = vb + vc + A2y;

        oe += __shfl_xor(oe, 8);  oo += __shfl_xor(oo, 8);
        oe += __shfl_xor(oe, 16); oo += __shfl_xor(oo, 16);
        oe += __shfl_xor(oe, 32); oo += __shfl_xor(oo, 32);

        if (g == 0) {
            const float* xp = x + (size_t)node * D + c0 + 2 * l;
            float xe = __builtin_nontemporal_load(xp);
            float xo = __builtin_nontemporal_load(xp + 1);
            float* op = out + (size_t)node * D + c0 + 2 * l;
            __builtin_nontemporal_store(r0 * xe + oe, op);
            __builtin_nontemporal_store(r0 * xo + oo, op + 1);
        }
    }
}

// overflow cleanup: wave per record, atomic add (expected ~0 records)
__global__ void ovf_kernel(const float* __restrict__ x,
                           const int* __restrict__ ovf_count,
                           const int4* __restrict__ ovf,
                           float* __restrict__ out) {
    int total_waves = (gridDim.x * blockDim.x) >> 6;
    int gw   = (blockIdx.x * blockDim.x + threadIdx.x) >> 6;
    int lane = threadIdx.x & 63;
    int n = *ovf_count;
    if (n > OVF_CAP) n = OVF_CAP;
    for (int r = gw; r < n; r += total_waves) {
        int4 rec = ovf[r];
        int src = rec.x;
        int dst = rec.y & 0x1FFFF;
        int sh  = (rec.y >> 17) & 3;
        float sc = __int_as_float(rec.z);
        const float* xr = x + (size_t)dst * D;
        float* orow = out + (size_t)src * D;
        int c0 = 2 * lane, c1 = 2 * lane + 1;
        atomicAdd(&orow[c0], sc * xr[(c0 - sh) & 127]);
        atomicAdd(&orow[c1], sc * xr[(c1 - sh) & 127]);
    }
}

// ===========================================================================
// MID TIER fallback (exact-CSR path, fp32 gather), if ws too small.
// ===========================================================================
#define SCAN_BLOCKS ((N_NODES + 255) / 256)   // 391
#define WS_COUNTS   0
#define WS_OFFSETS  400000
#define WS_CURSORS  800008
#define WS_BSUM     1200008
#define WS_BPRE     1201576
#define WS_RECS     1203144
#define WS_NEEDED_MID (WS_RECS + (size_t)TOT_EDGES * 8)

__global__ void hist_kernel(const int* __restrict__ ei1, const int* __restrict__ ei2,
                            const int* __restrict__ ei3, int* __restrict__ counts) {
    int e = blockIdx.x * blockDim.x + threadIdx.x;
    if (e >= TOT_EDGES) return;
    int set = e / N_EDGES;
    int idx = e - set * N_EDGES;
    const int* ei = (set == 0) ? ei1 : (set == 1) ? ei2 : ei3;
    atomicAdd(&counts[ei[idx]], 1);
}

__global__ void scan1_kernel(const int* __restrict__ counts,
                             int* __restrict__ offsets, int* __restrict__ bsum) {
    __shared__ int s[256];
    int t = threadIdx.x;
    int i = blockIdx.x * 256 + t;
    int v = (i < N_NODES) ? counts[i] : 0;
    s[t] = v;
    __syncthreads();
    for (int off = 1; off < 256; off <<= 1) {
        int u = (t >= off) ? s[t - off] : 0;
        __syncthreads();
        s[t] += u;
        __syncthreads();
    }
    if (i < N_NODES) offsets[i] = s[t] - v;
    if (t == 255) bsum[blockIdx.x] = s[255];
}

__global__ void scan2_kernel(const int* __restrict__ bsum, int* __restrict__ bpre) {
    __shared__ int s[512];
    int t = threadIdx.x;
    int v = (t < SCAN_BLOCKS) ? bsum[t] : 0;
    s[t] = v;
    __syncthreads();
    for (int off = 1; off < 512; off <<= 1) {
        int u = (t >= off) ? s[t - off] : 0;
        __syncthreads();
        s[t] += u;
        __syncthreads();
    }
    if (t < SCAN_BLOCKS) bpre[t] = s[t] - v;
}

__global__ void scan3_kernel(int* __restrict__ offsets, const int* __restrict__ bpre,
                             int* __restrict__ cursors) {
    int i = blockIdx.x * 256 + threadIdx.x;
    if (i < N_NODES) {
        int v = offsets[i] + bpre[blockIdx.x];
        offsets[i] = v;
        cursors[i] = v;
    }
    if (i == 0) offsets[N_NODES] = TOT_EDGES;
}

__global__ void fill_kernel(const int* __restrict__ ei1, const float* __restrict__ w1,
                            const int* __restrict__ ei2, const float* __restrict__ w2,
                            const int* __restrict__ ei3, const float* __restrict__ w3,
                            const float* __restrict__ z0, const float* __restrict__ z1,
                            const float* __restrict__ z2, const float* __restrict__ z3,
                            int* __restrict__ cursors, int2* __restrict__ recs) {
    int e = blockIdx.x * blockDim.x + threadIdx.x;
    if (e >= TOT_EDGES) return;
    int set = e / N_EDGES;
    int idx = e - set * N_EDGES;
    const int* ei;  const float* w;
    if      (set == 0) { ei = ei1; w = w1; }
    else if (set == 1) { ei = ei2; w = w2; }
    else               { ei = ei3; w = w3; }
    float r0, r1, r2, r3;
    load_r(z0, z1, z2, z3, r0, r1, r2, r3);
    float rk = (set == 0) ? r1 : (set == 1) ? r2 : r3;
    int src = ei[idx];
    int dst = ei[N_EDGES + idx];
    float scale = rk * w[idx];
    int pos = atomicAdd(&cursors[src], 1);
    recs[pos] = make_int2(dst | (set << 17), __float_as_int(scale));
}

__global__ void gatherd_kernel(const float* __restrict__ x,
                               const int* __restrict__ offsets,
                               const int2* __restrict__ recs,
                               const float* __restrict__ z0, const float* __restrict__ z1,
                               const float* __restrict__ z2, const float* __restrict__ z3,
                               float* __restrict__ out) {
    int wid  = (blockIdx.x * blockDim.x + threadIdx.x) >> 6;
    int lane = threadIdx.x & 63;
    if (wid >= N_NODES) return;
    float r0, r1, r2, r3;
    load_r(z0, z1, z2, z3, r0, r1, r2, r3);
    float2 xv = ((const float2*)(x + (size_t)wid * D))[lane];
    int beg = offsets[wid];
    int end = offsets[wid + 1];
    float2 a0 = {0.f, 0.f}, a1 = {0.f, 0.f}, a2 = {0.f, 0.f};
    for (int j = beg; j < end; ++j) {
        int2 rec = recs[j];
        float2 v = ((const float2*)(x + (size_t)(rec.x & 0x1FFFF) * D))[lane];
        int sh = (rec.x >> 17) & 3;
        float sc = __int_as_float(rec.y);
        if      (sh == 0) { a0.x += sc * v.x; a0.y += sc * v.y; }
        else if (sh == 1) { a1.x += sc * v.x; a1.y += sc * v.y; }
        else               { a2.x += sc * v.x; a2.y += sc * v.y; }
    }
    int prev = (lane + 63) & 63;
    float r1y = __shfl(a1.y, prev);
    float r2x = __shfl(a2.x, prev);
    float r2y = __shfl(a2.y, prev);
    float2 o;
    o.x = r0 * xv.x + a0.x + r1y  + r2x;
    o.y = r0 * xv.y + a0.y + a1.x + r2y;
    ((float2*)(out + (size_t)wid * D))[lane] = o;
}

extern "C" void kernel_launch(void* const* d_in, const int* in_sizes, int n_in,
                              void* d_out, int out_size, void* d_ws, size_t ws_size,
                              hipStream_t stream) {
    const float* x   = (const float*)d_in[0];
    const int*   ei1 = (const int*)  d_in[1];
    const float* w1  = (const float*)d_in[2];
    const int*   ei2 = (const int*)  d_in[3];
    const float* w2  = (const float*)d_in[4];
    const int*   ei3 = (const int*)  d_in[5];
    const float* w3  = (const float*)d_in[6];
    const float* z0  = (const float*)d_in[7];
    const float* z1  = (const float*)d_in[8];
    const float* z2  = (const float*)d_in[9];
    const float* z3  = (const float*)d_in[10];
    float* out = (float*)d_out;
    char* wsc = (char*)d_ws;

    if (ws_size >= WS_TOTAL_FAST) {
        int*  ovf_count = (int*) (wsc + WS_OVFCNT);
        int*  bcur      = (int*) (wsc + WS_BCUR);
        int4* ovf       = (int4*)(wsc + WS_OVF);
        int2* tmp       = (int2*)(wsc + WS_TMP);
        int*  offs      = (int*) (wsc + WS_OFFS);
        int*  cnts      = (int*) (wsc + WS_CNTS);
        char* xb3       =        (wsc + WS_XB3);

        hipMemsetAsync(wsc, 0, WS_OVF, stream);   // ovf_count + bucket cursors
        prep_kernel<<<BINA_BLOCKS + SCAST_BLOCKS, 256, 0, stream>>>(
            x, xb3, ei1, w1, ei2, w2, ei3, w3, z0, z1, z2, z3,
            bcur, ovf_count, ovf, tmp);
        binB_kernel<<<NB, 256, 0, stream>>>(bcur, tmp, offs, cnts);
        gslice_kernel<<<GATHER_BLOCKS, 256, 0, stream>>>(x, xb3, offs, cnts, tmp,
                                                         z0, z1, z2, z3, out);
        ovf_kernel<<<128, 256, 0, stream>>>(x, ovf_count, ovf, out);
    } else {
        int*  counts  = (int*) (wsc + WS_COUNTS);
        int*  offsets = (int*) (wsc + WS_OFFSETS);
        int*  cursors = (int*) (wsc + WS_CURSORS);
        int*  bsum    = (int*) (wsc + WS_BSUM);
        int*  bpre    = (int*) (wsc + WS_BPRE);
        int2* recs    = (int2*)(wsc + WS_RECS);

        hipMemsetAsync(counts, 0, N_NODES * sizeof(int), stream);
        hist_kernel<<<TOT_EDGES / 256, 256, 0, stream>>>(ei1, ei2, ei3, counts);
        scan1_kernel<<<SCAN_BLOCKS, 256, 0, stream>>>(counts, offsets, bsum);
        scan2_kernel<<<1, 512, 0, stream>>>(bsum, bpre);
        scan3_kernel<<<SCAN_BLOCKS, 256, 0, stream>>>(offsets, bpre, cursors);
        fill_kernel<<<TOT_EDGES / 256, 256, 0, stream>>>(ei1, w1, ei2, w2, ei3, w3,
                                                         z0, z1, z2, z3, cursors, recs);
        gatherd_kernel<<<(N_NODES * 64 + 255) / 256, 256, 0, stream>>>(x, offsets, recs,
                                                                       z0, z1, z2, z3, out);
    }
}

// Round 6
// 296.559 us; speedup vs baseline: 2.1112x; 2.1112x over previous
//
#include <hip/hip_runtime.h>

#define N_NODES 100000
#define D 128
#define N_EDGES 640000
#define TOT_EDGES (3 * N_EDGES)   // 1,920,000

#define NB   1024                 // buckets (node ranges)
#define NPB  98                   // nodes per bucket (1024*98 >= 100000)
#define BCAP 2304                 // record cap per bucket (mean 1875, ~+10 sigma; 9*256)
#define RPT  9                    // records per thread in binB (BCAP/256)
#define OVF_CAP 16384
#define NKEY 512                  // pow2 >= NPB*4 (local*4+set sort key space)

#define EPBA 2560                 // edges per histA/placeA block
#define SETBLKA (N_EDGES / EPBA)  // 250 blocks per edge set
#define BLKA (3 * SETBLKA)        // 750
#define EPT2 (EPBA / 256)         // 10 edges per thread

#define CAST_BLOCKS ((N_NODES * D / 4 + 255) / 256)   // 12500

// ---------------- fast-path ws layout (bytes); total 48,612,672 ------------
#define WS_OVFCNT 0
#define WS_CNT    64                         // int[BLKA*NB] counts -> bases, 3 MB
#define WS_TOT    3072064                    // int[NB] totals
#define WS_OVF    3076160                    // int4[OVF_CAP], 256 KB
#define WS_TMP    3338304                    // int2[NB*BCAP], 18.87 MB (sorted in place)
#define WS_OFFS   22212672                   // int[N_NODES] abs index into tmp
#define WS_CNTS   22612672                   // int[N_NODES]
#define WS_XB     23012672                   // ushort[N_NODES*D] bf16, 25.6 MB
#define WS_TOTAL_FAST 48612672

#ifndef __has_builtin
#define __has_builtin(x) 0
#endif
#if __has_builtin(__builtin_amdgcn_alignbit)
#define ALIGN16(hi, lo) __builtin_amdgcn_alignbit((hi), (lo), 16)
#else
#define ALIGN16(hi, lo) (((hi) << 16) | ((lo) >> 16))
#endif

__device__ __forceinline__ void load_r(const float* z0, const float* z1,
                                       const float* z2, const float* z3,
                                       float& r0, float& r1, float& r2, float& r3) {
    r0 = fmaxf(z0[0], 0.0f);
    r1 = fmaxf(z1[0], 0.0f);
    r2 = fmaxf(z2[0], 0.0f);
    r3 = fmaxf(z3[0], 0.0f);
    float inv = 1.0f / (r0 + r1 + r2 + r3 + 1e-6f);
    r0 *= inv; r1 *= inv; r2 *= inv; r3 *= inv;
}

__device__ __forceinline__ unsigned short bf16rn(float f) {
    unsigned int u = __float_as_uint(f);
    u += 0x7FFFu + ((u >> 16) & 1u);   // round to nearest even
    return (unsigned short)(u >> 16);
}

// ---- cast x -> bf16 copy (halves gather traffic) ---------------------------
__global__ __launch_bounds__(256) void cast_kernel(const float* __restrict__ x,
                                                   ushort* __restrict__ xb) {
    int i = blockIdx.x * 256 + threadIdx.x;
    if (i >= N_NODES * D / 4) return;
    float4 v = ((const float4*)x)[i];
    ushort4 h;
    h.x = bf16rn(v.x); h.y = bf16rn(v.y); h.z = bf16rn(v.z); h.w = bf16rn(v.w);
    ((ushort4*)xb)[i] = h;
}

// ---------------------------------------------------------------------------
// histA: per-block LDS histogram of edge srcs over 1024 buckets -> counts.
// Deterministic (no global atomics anywhere in the binning pipeline).
// ---------------------------------------------------------------------------
__global__ __launch_bounds__(256) void histA_kernel(
        const int* __restrict__ ei1, const int* __restrict__ ei2,
        const int* __restrict__ ei3, int* __restrict__ counts) {
    __shared__ int h[NB];
    int t = threadIdx.x;
    int blk = blockIdx.x;
    for (int i = t; i < NB; i += 256) h[i] = 0;
    __syncthreads();
    int set = blk / SETBLKA;
    int e0  = (blk - set * SETBLKA) * EPBA;
    const int* ei = (set == 0) ? ei1 : (set == 1) ? ei2 : ei3;
    for (int i = t; i < EPBA; i += 256) {
        atomicAdd(&h[ei[e0 + i] / NPB], 1);
    }
    __syncthreads();
    for (int i = t; i < NB; i += 256) counts[blk * NB + i] = h[i];
}

// scanA: per bucket, exclusive scan over the 750 block counts (in place:
// counts becomes per-(block,bucket) base) + per-bucket totals.
__global__ __launch_bounds__(256) void scanA_kernel(int* __restrict__ counts,
                                                    int* __restrict__ totals) {
    int b = blockIdx.x * 256 + threadIdx.x;   // 4 blocks x 256 = 1024 buckets
    int run = 0;
    for (int blk = 0; blk < BLKA; ++blk) {
        int c = counts[blk * NB + b];
        counts[blk * NB + b] = run;
        run += c;
    }
    totals[b] = run;
}

// ---------------------------------------------------------------------------
// placeA: re-read edges, rank via fresh LDS hist (any within-block permutation
// is valid), counting-sort the block's 2560 records into LDS by bucket, then
// flush in bucket-sorted order -> wave stores hit runs of consecutive tmp
// addresses (kills the 64-lines-per-store scatter of previous binA versions).
// tmp rec: x = dst(17)|set<<17(2)|local<<19(7), y = f32 scale.
// ---------------------------------------------------------------------------
__global__ __launch_bounds__(256) void placeA_kernel(
        const int* __restrict__ ei1, const float* __restrict__ w1,
        const int* __restrict__ ei2, const float* __restrict__ w2,
        const int* __restrict__ ei3, const float* __restrict__ w3,
        const float* __restrict__ z0, const float* __restrict__ z1,
        const float* __restrict__ z2, const float* __restrict__ z3,
        const int* __restrict__ bbase,   // per-(block,bucket) base (from scanA)
        int* __restrict__ ovf_count, int4* __restrict__ ovf,
        int2* __restrict__ tmp) {
    __shared__ int bb[NB];        // 4 KB
    __shared__ int h[NB];         // 4 KB (hist, then reused as scatter cursor)
    __shared__ int ts[256];       // 1 KB
    __shared__ int2 srec[EPBA];   // 20 KB
    __shared__ int gx[EPBA];      // 10 KB

    int t = threadIdx.x;
    int blk = blockIdx.x;
    for (int i = t; i < NB; i += 256) { bb[i] = bbase[blk * NB + i]; h[i] = 0; }
    __syncthreads();

    int set = blk / SETBLKA;
    int e0  = (blk - set * SETBLKA) * EPBA;
    const int* ei;  const float* w;  float rk;
    float r0, r1, r2, r3;
    load_r(z0, z1, z2, z3, r0, r1, r2, r3);
    if      (set == 0) { ei = ei1; w = w1; rk = r1; }
    else if (set == 1) { ei = ei2; w = w2; rk = r2; }
    else               { ei = ei3; w = w3; rk = r3; }

    int bkt[EPT2], rnk[EPT2], lcl[EPT2], dstv[EPT2];
    float scv[EPT2];
#pragma unroll
    for (int k = 0; k < EPT2; ++k) {
        int idx = e0 + t + k * 256;
        int src = ei[idx];
        dstv[k] = ei[N_EDGES + idx];
        scv[k]  = rk * w[idx];
        int b = src / NPB;
        bkt[k] = b;
        lcl[k] = src - b * NPB;
        rnk[k] = atomicAdd(&h[b], 1);
    }
    __syncthreads();

    // exclusive scan of h[0..NB) -> h (thread t owns keys 4t..4t+3)
    int loc[4];
    int tot = 0;
#pragma unroll
    for (int k = 0; k < 4; ++k) { loc[k] = tot; tot += h[4 * t + k]; }
    ts[t] = tot;
    __syncthreads();
    for (int off = 1; off < 256; off <<= 1) {
        int v = (t >= off) ? ts[t - off] : 0;
        __syncthreads();
        ts[t] += v;
        __syncthreads();
    }
    int tb = ts[t] - tot;
    __syncthreads();
#pragma unroll
    for (int k = 0; k < 4; ++k) h[4 * t + k] = tb + loc[k];
    __syncthreads();

    // scatter into bucket-sorted LDS order + compute global dest index
#pragma unroll
    for (int k = 0; k < EPT2; ++k) {
        int b = bkt[k];
        int s = h[b] + rnk[k];
        int rx = dstv[k] | (set << 17) | (lcl[k] << 19);
        srec[s] = make_int2(rx, __float_as_int(scv[k]));
        int p = bb[b] + rnk[k];
        if (p < BCAP) {
            gx[s] = b * BCAP + p;
        } else {
            gx[s] = -1;
            int o = atomicAdd(ovf_count, 1);
            if (o < OVF_CAP) ovf[o] = make_int4(b * NPB + lcl[k],
                                               dstv[k] | (set << 17),
                                               __float_as_int(scv[k]), 0);
        }
    }
    __syncthreads();

    // coalesced-ish flush (consecutive s -> mostly consecutive tmp addresses)
    for (int s = t; s < EPBA; s += 256) {
        int g = gx[s];
        if (g >= 0) tmp[g] = srec[s];
    }
}

// ---------------------------------------------------------------------------
// binB: per-bucket counting sort by key = local*4+set, IN PLACE in tmp.
// Emits per-node CSR (offs = absolute index into tmp, cnts = degree).
// ---------------------------------------------------------------------------
__global__ __launch_bounds__(256) void binB_kernel(
        const int* __restrict__ totals, int2* __restrict__ tmp,
        int* __restrict__ offs, int* __restrict__ cnts) {
    __shared__ int dH[NKEY];
    __shared__ int ts[256];
    __shared__ int cur[NKEY];
    __shared__ int nb[NPB + 1];
    int b = blockIdx.x;
    int t = threadIdx.x;
    int n = totals[b];
    if (n > BCAP) n = BCAP;

    int mrx[RPT], mry[RPT];
#pragma unroll
    for (int k = 0; k < RPT; ++k) {
        int i = t + k * 256;
        if (i < n) { int2 r = tmp[(size_t)b * BCAP + i]; mrx[k] = r.x; mry[k] = r.y; }
        else       { mrx[k] = -1; mry[k] = 0; }
    }

    dH[t] = 0; dH[t + 256] = 0;
    __syncthreads();
#pragma unroll
    for (int k = 0; k < RPT; ++k) {
        if (mrx[k] != -1) {
            int key = (((mrx[k] >> 19) & 0x7F) << 2) | ((mrx[k] >> 17) & 3);
            atomicAdd(&dH[key], 1);
        }
    }
    __syncthreads();

    int k0 = dH[2 * t], k1 = dH[2 * t + 1];
    int tot = k0 + k1;
    ts[t] = tot;
    __syncthreads();
    for (int off = 1; off < 256; off <<= 1) {
        int v = (t >= off) ? ts[t - off] : 0;
        __syncthreads();
        ts[t] += v;
        __syncthreads();
    }
    int tb = ts[t] - tot;
    cur[2 * t]     = tb;
    cur[2 * t + 1] = tb + k0;
    __syncthreads();

    if (t <= NPB) nb[t] = (t < NPB) ? cur[t << 2] : n;
    __syncthreads();

#pragma unroll
    for (int k = 0; k < RPT; ++k) {
        if (mrx[k] != -1) {
            int key = (((mrx[k] >> 19) & 0x7F) << 2) | ((mrx[k] >> 17) & 3);
            int pos = atomicAdd(&cur[key], 1);
            tmp[(size_t)b * BCAP + pos] = make_int2(mrx[k], mry[k]);
        }
    }

    if (t < NPB) {
        int node = b * NPB + t;
        if (node < N_NODES) {
            offs[node] = b * BCAP + nb[t];
            cnts[node] = nb[t + 1] - nb[t];
        }
    }
}

// ---------------------------------------------------------------------------
// gatherb (R2-proven body, 102 us): wave per node; 4 records per round, each
// row read by one 16-lane quarter as uint4. Rotation at load time via packed
// bf16x2 word shift; 8 named scalar accumulators (no aggregates, no scratch).
// ---------------------------------------------------------------------------
#define GB_ACCUM(RX, RY)                                                       \
    {                                                                          \
        const uint4* rowp = (const uint4*)(xb + (size_t)((RX) & 0x1FFFF) * D); \
        uint4 v = rowp[l16];                                                   \
        int sh = ((RX) >> 17) & 3;                                             \
        float sc = __int_as_float(RY);                                         \
        unsigned int pw = (unsigned int)__shfl((int)v.w, prevq);               \
        unsigned int s1x = ALIGN16(v.x, pw);                                   \
        unsigned int s1y = ALIGN16(v.y, v.x);                                  \
        unsigned int s1z = ALIGN16(v.z, v.y);                                  \
        unsigned int s1w = ALIGN16(v.w, v.z);                                  \
        unsigned int u0 = (sh == 0) ? v.x : (sh == 1) ? s1x : pw;              \
        unsigned int u1 = (sh == 0) ? v.y : (sh == 1) ? s1y : v.x;             \
        unsigned int u2 = (sh == 0) ? v.z : (sh == 1) ? s1z : v.y;             \
        unsigned int u3 = (sh == 0) ? v.w : (sh == 1) ? s1w : v.z;             \
        acc0 += sc * __uint_as_float(u0 << 16);                                \
        acc1 += sc * __uint_as_float(u0 & 0xFFFF0000u);                        \
        acc2 += sc * __uint_as_float(u1 << 16);                                \
        acc3 += sc * __uint_as_float(u1 & 0xFFFF0000u);                        \
        acc4 += sc * __uint_as_float(u2 << 16);                                \
        acc5 += sc * __uint_as_float(u2 & 0xFFFF0000u);                        \
        acc6 += sc * __uint_as_float(u3 << 16);                                \
        acc7 += sc * __uint_as_float(u3 & 0xFFFF0000u);                        \
    }

__global__ __launch_bounds__(256) void gatherb_kernel(
        const float* __restrict__ x, const ushort* __restrict__ xb,
        const int* __restrict__ offs, const int* __restrict__ cnts,
        const int2* __restrict__ recs,
        const float* __restrict__ z0, const float* __restrict__ z1,
        const float* __restrict__ z2, const float* __restrict__ z3,
        float* __restrict__ out) {
    int wid  = (blockIdx.x * blockDim.x + threadIdx.x) >> 6;
    int lane = threadIdx.x & 63;
    if (wid >= N_NODES) return;

    float r0, r1, r2, r3;
    load_r(z0, z1, z2, z3, r0, r1, r2, r3);

    int qt    = lane >> 4;                    // record slot within 4-group
    int l16   = lane & 15;                    // 16 lanes x uint4 = 256 B row
    int prevq = (qt << 4) | ((l16 + 15) & 15);

    int beg   = offs[wid];
    int count = cnts[wid];
    int cnt64 = (count < 64) ? count : 64;

    int mrx = 0, mry = 0;                     // pad: row 0, scale 0
    if (lane < cnt64) { int2 rec = recs[beg + lane]; mrx = rec.x; mry = rec.y; }

    float acc0 = 0.f, acc1 = 0.f, acc2 = 0.f, acc3 = 0.f;
    float acc4 = 0.f, acc5 = 0.f, acc6 = 0.f, acc7 = 0.f;

    for (int j = 0; j < cnt64; j += 4) {
        int srcl = j + qt;                    // <= 63 always (j <= 60)
        int rx = __shfl(mrx, srcl);
        int ry = __shfl(mry, srcl);
        GB_ACCUM(rx, ry)
    }
    for (int q = 64; q < count; q += 4) {     // rare high-degree tail
        int qq = q + qt;
        int rx = 0, ry = 0;
        if (qq < count) { int2 rec = recs[beg + qq]; rx = rec.x; ry = rec.y; }
        GB_ACCUM(rx, ry)
    }

    acc0 += __shfl_xor(acc0, 16); acc0 += __shfl_xor(acc0, 32);
    acc1 += __shfl_xor(acc1, 16); acc1 += __shfl_xor(acc1, 32);
    acc2 += __shfl_xor(acc2, 16); acc2 += __shfl_xor(acc2, 32);
    acc3 += __shfl_xor(acc3, 16); acc3 += __shfl_xor(acc3, 32);
    acc4 += __shfl_xor(acc4, 16); acc4 += __shfl_xor(acc4, 32);
    acc5 += __shfl_xor(acc5, 16); acc5 += __shfl_xor(acc5, 32);
    acc6 += __shfl_xor(acc6, 16); acc6 += __shfl_xor(acc6, 32);
    acc7 += __shfl_xor(acc7, 16); acc7 += __shfl_xor(acc7, 32);

    if (lane < 16) {
        const float4* xr = (const float4*)(x + (size_t)wid * D);
        float4 xlo = xr[2 * l16];
        float4 xhi = xr[2 * l16 + 1];
        float4 olo, ohi;
        olo.x = r0 * xlo.x + acc0;
        olo.y = r0 * xlo.y + acc1;
        olo.z = r0 * xlo.z + acc2;
        olo.w = r0 * xlo.w + acc3;
        ohi.x = r0 * xhi.x + acc4;
        ohi.y = r0 * xhi.y + acc5;
        ohi.z = r0 * xhi.z + acc6;
        ohi.w = r0 * xhi.w + acc7;
        float4* op = (float4*)(out + (size_t)wid * D);
        op[2 * l16]     = olo;
        op[2 * l16 + 1] = ohi;
    }
}

// overflow cleanup: wave per record, atomic add (expected ~0 records)
__global__ void ovf_kernel(const float* __restrict__ x,
                           const int* __restrict__ ovf_count,
                           const int4* __restrict__ ovf,
                           float* __restrict__ out) {
    int total_waves = (gridDim.x * blockDim.x) >> 6;
    int gw   = (blockIdx.x * blockDim.x + threadIdx.x) >> 6;
    int lane = threadIdx.x & 63;
    int n = *ovf_count;
    if (n > OVF_CAP) n = OVF_CAP;
    for (int r = gw; r < n; r += total_waves) {
        int4 rec = ovf[r];
        int src = rec.x;
        int dst = rec.y & 0x1FFFF;
        int sh  = (rec.y >> 17) & 3;
        float sc = __int_as_float(rec.z);
        const float* xr = x + (size_t)dst * D;
        float* orow = out + (size_t)src * D;
        int c0 = 2 * lane, c1 = 2 * lane + 1;
        atomicAdd(&orow[c0], sc * xr[(c0 - sh) & 127]);
        atomicAdd(&orow[c1], sc * xr[(c1 - sh) & 127]);
    }
}

// ===========================================================================
// MID TIER fallback (exact-CSR path, fp32 gather), if ws too small.
// ===========================================================================
#define SCAN_BLOCKS ((N_NODES + 255) / 256)   // 391
#define WS_COUNTS   0
#define WS_OFFSETS  400000
#define WS_CURSORS  800008
#define WS_BSUM     1200008
#define WS_BPRE     1201576
#define WS_RECS     1203144
#define WS_NEEDED_MID (WS_RECS + (size_t)TOT_EDGES * 8)

__global__ void hist_kernel(const int* __restrict__ ei1, const int* __restrict__ ei2,
                            const int* __restrict__ ei3, int* __restrict__ counts) {
    int e = blockIdx.x * blockDim.x + threadIdx.x;
    if (e >= TOT_EDGES) return;
    int set = e / N_EDGES;
    int idx = e - set * N_EDGES;
    const int* ei = (set == 0) ? ei1 : (set == 1) ? ei2 : ei3;
    atomicAdd(&counts[ei[idx]], 1);
}

__global__ void scan1_kernel(const int* __restrict__ counts,
                             int* __restrict__ offsets, int* __restrict__ bsum) {
    __shared__ int s[256];
    int t = threadIdx.x;
    int i = blockIdx.x * 256 + t;
    int v = (i < N_NODES) ? counts[i] : 0;
    s[t] = v;
    __syncthreads();
    for (int off = 1; off < 256; off <<= 1) {
        int u = (t >= off) ? s[t - off] : 0;
        __syncthreads();
        s[t] += u;
        __syncthreads();
    }
    if (i < N_NODES) offsets[i] = s[t] - v;
    if (t == 255) bsum[blockIdx.x] = s[255];
}

__global__ void scan2_kernel(const int* __restrict__ bsum, int* __restrict__ bpre) {
    __shared__ int s[512];
    int t = threadIdx.x;
    int v = (t < SCAN_BLOCKS) ? bsum[t] : 0;
    s[t] = v;
    __syncthreads();
    for (int off = 1; off < 512; off <<= 1) {
        int u = (t >= off) ? s[t - off] : 0;
        __syncthreads();
        s[t] += u;
        __syncthreads();
    }
    if (t < SCAN_BLOCKS) bpre[t] = s[t] - v;
}

__global__ void scan3_kernel(int* __restrict__ offsets, const int* __restrict__ bpre,
                             int* __restrict__ cursors) {
    int i = blockIdx.x * 256 + threadIdx.x;
    if (i < N_NODES) {
        int v = offsets[i] + bpre[blockIdx.x];
        offsets[i] = v;
        cursors[i] = v;
    }
    if (i == 0) offsets[N_NODES] = TOT_EDGES;
}

__global__ void fill_kernel(const int* __restrict__ ei1, const float* __restrict__ w1,
                            const int* __restrict__ ei2, const float* __restrict__ w2,
                            const int* __restrict__ ei3, const float* __restrict__ w3,
                            const float* __restrict__ z0, const float* __restrict__ z1,
                            const float* __restrict__ z2, const float* __restrict__ z3,
                            int* __restrict__ cursors, int2* __restrict__ recs) {
    int e = blockIdx.x * blockDim.x + threadIdx.x;
    if (e >= TOT_EDGES) return;
    int set = e / N_EDGES;
    int idx = e - set * N_EDGES;
    const int* ei;  const float* w;
    if      (set == 0) { ei = ei1; w = w1; }
    else if (set == 1) { ei = ei2; w = w2; }
    else               { ei = ei3; w = w3; }
    float r0, r1, r2, r3;
    load_r(z0, z1, z2, z3, r0, r1, r2, r3);
    float rk = (set == 0) ? r1 : (set == 1) ? r2 : r3;
    int src = ei[idx];
    int dst = ei[N_EDGES + idx];
    float scale = rk * w[idx];
    int pos = atomicAdd(&cursors[src], 1);
    recs[pos] = make_int2(dst | (set << 17), __float_as_int(scale));
}

__global__ void gatherd_kernel(const float* __restrict__ x,
                               const int* __restrict__ offsets,
                               const int2* __restrict__ recs,
                               const float* __restrict__ z0, const float* __restrict__ z1,
                               const float* __restrict__ z2, const float* __restrict__ z3,
                               float* __restrict__ out) {
    int wid  = (blockIdx.x * blockDim.x + threadIdx.x) >> 6;
    int lane = threadIdx.x & 63;
    if (wid >= N_NODES) return;
    float r0, r1, r2, r3;
    load_r(z0, z1, z2, z3, r0, r1, r2, r3);
    float2 xv = ((const float2*)(x + (size_t)wid * D))[lane];
    int beg = offsets[wid];
    int end = offsets[wid + 1];
    float2 a0 = {0.f, 0.f}, a1 = {0.f, 0.f}, a2 = {0.f, 0.f};
    for (int j = beg; j < end; ++j) {
        int2 rec = recs[j];
        float2 v = ((const float2*)(x + (size_t)(rec.x & 0x1FFFF) * D))[lane];
        int sh = (rec.x >> 17) & 3;
        float sc = __int_as_float(rec.y);
        if      (sh == 0) { a0.x += sc * v.x; a0.y += sc * v.y; }
        else if (sh == 1) { a1.x += sc * v.x; a1.y += sc * v.y; }
        else               { a2.x += sc * v.x; a2.y += sc * v.y; }
    }
    int prev = (lane + 63) & 63;
    float r1y = __shfl(a1.y, prev);
    float r2x = __shfl(a2.x, prev);
    float r2y = __shfl(a2.y, prev);
    float2 o;
    o.x = r0 * xv.x + a0.x + r1y  + r2x;
    o.y = r0 * xv.y + a0.y + a1.x + r2y;
    ((float2*)(out + (size_t)wid * D))[lane] = o;
}

extern "C" void kernel_launch(void* const* d_in, const int* in_sizes, int n_in,
                              void* d_out, int out_size, void* d_ws, size_t ws_size,
                              hipStream_t stream) {
    const float* x   = (const float*)d_in[0];
    const int*   ei1 = (const int*)  d_in[1];
    const float* w1  = (const float*)d_in[2];
    const int*   ei2 = (const int*)  d_in[3];
    const float* w2  = (const float*)d_in[4];
    const int*   ei3 = (const int*)  d_in[5];
    const float* w3  = (const float*)d_in[6];
    const float* z0  = (const float*)d_in[7];
    const float* z1  = (const float*)d_in[8];
    const float* z2  = (const float*)d_in[9];
    const float* z3  = (const float*)d_in[10];
    float* out = (float*)d_out;
    char* wsc = (char*)d_ws;

    if (ws_size >= WS_TOTAL_FAST) {
        int*    ovf_count = (int*)   (wsc + WS_OVFCNT);
        int*    counts    = (int*)   (wsc + WS_CNT);
        int*    totals    = (int*)   (wsc + WS_TOT);
        int4*   ovf       = (int4*)  (wsc + WS_OVF);
        int2*   tmp       = (int2*)  (wsc + WS_TMP);
        int*    offs      = (int*)   (wsc + WS_OFFS);
        int*    cnts      = (int*)   (wsc + WS_CNTS);
        ushort* xb        = (ushort*)(wsc + WS_XB);

        hipMemsetAsync(wsc, 0, 64, stream);   // ovf_count
        cast_kernel<<<CAST_BLOCKS, 256, 0, stream>>>(x, xb);
        histA_kernel<<<BLKA, 256, 0, stream>>>(ei1, ei2, ei3, counts);
        scanA_kernel<<<4, 256, 0, stream>>>(counts, totals);
        placeA_kernel<<<BLKA, 256, 0, stream>>>(ei1, w1, ei2, w2, ei3, w3,
                                                z0, z1, z2, z3,
                                                counts, ovf_count, ovf, tmp);
        binB_kernel<<<NB, 256, 0, stream>>>(totals, tmp, offs, cnts);
        gatherb_kernel<<<(N_NODES * 64 + 255) / 256, 256, 0, stream>>>(
            x, xb, offs, cnts, tmp, z0, z1, z2, z3, out);
        ovf_kernel<<<128, 256, 0, stream>>>(x, ovf_count, ovf, out);
    } else {
        int*  counts  = (int*) (wsc + WS_COUNTS);
        int*  offsets = (int*) (wsc + WS_OFFSETS);
        int*  cursors = (int*) (wsc + WS_CURSORS);
        int*  bsum    = (int*) (wsc + WS_BSUM);
        int*  bpre    = (int*) (wsc + WS_BPRE);
        int2* recs    = (int2*)(wsc + WS_RECS);

        hipMemsetAsync(counts, 0, N_NODES * sizeof(int), stream);
        hist_kernel<<<TOT_EDGES / 256, 256, 0, stream>>>(ei1, ei2, ei3, counts);
        scan1_kernel<<<SCAN_BLOCKS, 256, 0, stream>>>(counts, offsets, bsum);
        scan2_kernel<<<1, 512, 0, stream>>>(bsum, bpre);
        scan3_kernel<<<SCAN_BLOCKS, 256, 0, stream>>>(offsets, bpre, cursors);
        fill_kernel<<<TOT_EDGES / 256, 256, 0, stream>>>(ei1, w1, ei2, w2, ei3, w3,
                                                         z0, z1, z2, z3, cursors, recs);
        gatherd_kernel<<<(N_NODES * 64 + 255) / 256, 256, 0, stream>>>(x, offsets, recs,
                                                                       z0, z1, z2, z3, out);
    }
}

// Round 7
// 286.792 us; speedup vs baseline: 2.1831x; 1.0341x over previous
//
#include <hip/hip_runtime.h>

#define N_NODES 100000
#define D 128
#define N_EDGES 640000
#define TOT_EDGES (3 * N_EDGES)   // 1,920,000

#define NB   1024                 // buckets (node ranges)
#define NPB  98                   // nodes per bucket (1024*98 >= 100000)
#define BCAP 2304                 // record cap per bucket (mean 1875, ~+10 sigma; 9*256)
#define RPT  9                    // records per thread in binB (BCAP/256)
#define OVF_CAP 16384
#define NKEY 512                  // pow2 >= NPB*4 (local*4+set sort key space)

#define EPBA 2560                 // edges per binA block (divides N_EDGES)
#define SETBLKA (N_EDGES / EPBA)  // 250 blocks per edge set
#define BLKA (3 * SETBLKA)        // 750
#define EPT2 (EPBA / 256)         // 10 edges per thread

#define CAST_BLOCKS ((N_NODES * D / 4 + 255) / 256)   // 12500

// ---------------- fast-path ws layout (bytes); total 45,602,112 ------------
#define WS_OVFCNT 0
#define WS_BCUR   64                         // int, stride 16 ints (64B/bucket) x1024
#define WS_OVF    65600                      // int4[OVF_CAP], 256 KB
#define WS_TMP    327744                     // int2[NB*BCAP], 18.87 MB (sorted in place)
#define WS_OFFS   19202112                   // int[N_NODES] abs index into tmp
#define WS_CNTS   19602112                   // int[N_NODES]
#define WS_XB     20002112                   // ushort[N_NODES*D] bf16, 25.6 MB
#define WS_TOTAL_FAST 45602112

#ifndef __has_builtin
#define __has_builtin(x) 0
#endif
#if __has_builtin(__builtin_amdgcn_alignbit)
#define ALIGN16(hi, lo) __builtin_amdgcn_alignbit((hi), (lo), 16)
#else
#define ALIGN16(hi, lo) (((hi) << 16) | ((lo) >> 16))
#endif

__device__ __forceinline__ void load_r(const float* z0, const float* z1,
                                       const float* z2, const float* z3,
                                       float& r0, float& r1, float& r2, float& r3) {
    r0 = fmaxf(z0[0], 0.0f);
    r1 = fmaxf(z1[0], 0.0f);
    r2 = fmaxf(z2[0], 0.0f);
    r3 = fmaxf(z3[0], 0.0f);
    float inv = 1.0f / (r0 + r1 + r2 + r3 + 1e-6f);
    r0 *= inv; r1 *= inv; r2 *= inv; r3 *= inv;
}

__device__ __forceinline__ unsigned short bf16rn(float f) {
    unsigned int u = __float_as_uint(f);
    u += 0x7FFFu + ((u >> 16) & 1u);   // round to nearest even
    return (unsigned short)(u >> 16);
}

// ---------------------------------------------------------------------------
// prep: merged cast (x -> bf16 xb) + binA. binA = LDS histogram + ONE global
// atomicAdd per (block,bucket) for bases (no serial scan kernel, no edge
// re-read) + LDS counting-sort of the block's 2560 records + coalesced flush
// in bucket-sorted order (keeps R6's scatter-write fix).
// tmp rec: x = dst(17)|set<<17(2)|local<<19(7), y = f32 scale.
// ---------------------------------------------------------------------------
__global__ __launch_bounds__(256) void prep_kernel(
        const float* __restrict__ x, ushort* __restrict__ xb,
        const int* __restrict__ ei1, const float* __restrict__ w1,
        const int* __restrict__ ei2, const float* __restrict__ w2,
        const int* __restrict__ ei3, const float* __restrict__ w3,
        const float* __restrict__ z0, const float* __restrict__ z1,
        const float* __restrict__ z2, const float* __restrict__ z3,
        int* __restrict__ bcur, int* __restrict__ ovf_count,
        int4* __restrict__ ovf, int2* __restrict__ tmp) {
    if (blockIdx.x >= BLKA) {
        // ---- cast branch ----
        int i = (blockIdx.x - BLKA) * 256 + threadIdx.x;
        if (i < N_NODES * D / 4) {
            float4 v = ((const float4*)x)[i];
            ushort4 h4;
            h4.x = bf16rn(v.x); h4.y = bf16rn(v.y);
            h4.z = bf16rn(v.z); h4.w = bf16rn(v.w);
            ((ushort4*)xb)[i] = h4;
        }
        return;
    }
    // ---- binA branch ----
    __shared__ int bb[NB];        // 4 KB  global base per bucket
    __shared__ int h[NB];         // 4 KB  hist -> local excl base
    __shared__ int ts[256];       // 1 KB
    __shared__ int2 srec[EPBA];   // 20 KB sorted records
    __shared__ int gx[EPBA];      // 10 KB global dest per sorted slot

    int t = threadIdx.x;
    int blk = blockIdx.x;
    for (int i = t; i < NB; i += 256) h[i] = 0;
    __syncthreads();

    float r0, r1, r2, r3;
    load_r(z0, z1, z2, z3, r0, r1, r2, r3);

    int set = blk / SETBLKA;
    int e0  = (blk - set * SETBLKA) * EPBA;
    const int* ei;  const float* w;  float rk;
    if      (set == 0) { ei = ei1; w = w1; rk = r1; }
    else if (set == 1) { ei = ei2; w = w2; rk = r2; }
    else               { ei = ei3; w = w3; rk = r3; }

    int bkt[EPT2], rnk[EPT2], lcl[EPT2], dstv[EPT2];
    float scv[EPT2];
#pragma unroll
    for (int k = 0; k < EPT2; ++k) {
        int idx = e0 + t + k * 256;
        int src = ei[idx];
        dstv[k] = ei[N_EDGES + idx];
        scv[k]  = rk * w[idx];
        int b = src / NPB;
        bkt[k] = b;
        lcl[k] = src - b * NPB;
        rnk[k] = atomicAdd(&h[b], 1);
    }
    __syncthreads();

    // global bases (one atomic per nonempty bucket) + read hist for scan
    int loc[4];
    int tot = 0;
#pragma unroll
    for (int k = 0; k < 4; ++k) { loc[k] = tot; tot += h[4 * t + k]; }
    for (int i = t; i < NB; i += 256) {
        int c = h[i];
        bb[i] = c ? atomicAdd(&bcur[i * 16], c) : 0;
    }
    ts[t] = tot;
    __syncthreads();
    for (int off = 1; off < 256; off <<= 1) {
        int v = (t >= off) ? ts[t - off] : 0;
        __syncthreads();
        ts[t] += v;
        __syncthreads();
    }
    int tb = ts[t] - tot;
    __syncthreads();
#pragma unroll
    for (int k = 0; k < 4; ++k) h[4 * t + k] = tb + loc[k];
    __syncthreads();

    // scatter into bucket-sorted LDS order + compute global dest index
#pragma unroll
    for (int k = 0; k < EPT2; ++k) {
        int b = bkt[k];
        int s = h[b] + rnk[k];
        int rx = dstv[k] | (set << 17) | (lcl[k] << 19);
        srec[s] = make_int2(rx, __float_as_int(scv[k]));
        int p = bb[b] + rnk[k];
        if (p < BCAP) {
            gx[s] = b * BCAP + p;
        } else {
            gx[s] = -1;
            int o = atomicAdd(ovf_count, 1);
            if (o < OVF_CAP) ovf[o] = make_int4(b * NPB + lcl[k],
                                               dstv[k] | (set << 17),
                                               __float_as_int(scv[k]), 0);
        }
    }
    __syncthreads();

    // coalesced-ish flush (consecutive s -> consecutive tmp addresses per run)
    for (int s = t; s < EPBA; s += 256) {
        int g = gx[s];
        if (g >= 0) tmp[g] = srec[s];
    }
}

// ---------------------------------------------------------------------------
// binB: per-bucket counting sort by key = local*4+set, IN PLACE in tmp.
// Emits per-node CSR (offs = absolute index into tmp, cnts = degree).
// ---------------------------------------------------------------------------
__global__ __launch_bounds__(256) void binB_kernel(
        const int* __restrict__ bcur, int2* __restrict__ tmp,
        int* __restrict__ offs, int* __restrict__ cnts) {
    __shared__ int dH[NKEY];
    __shared__ int ts[256];
    __shared__ int cur[NKEY];
    __shared__ int nb[NPB + 1];
    int b = blockIdx.x;
    int t = threadIdx.x;
    int n = bcur[b * 16];
    if (n > BCAP) n = BCAP;

    int mrx[RPT], mry[RPT];
#pragma unroll
    for (int k = 0; k < RPT; ++k) {
        int i = t + k * 256;
        if (i < n) { int2 r = tmp[(size_t)b * BCAP + i]; mrx[k] = r.x; mry[k] = r.y; }
        else       { mrx[k] = -1; mry[k] = 0; }
    }

    dH[t] = 0; dH[t + 256] = 0;
    __syncthreads();
#pragma unroll
    for (int k = 0; k < RPT; ++k) {
        if (mrx[k] != -1) {
            int key = (((mrx[k] >> 19) & 0x7F) << 2) | ((mrx[k] >> 17) & 3);
            atomicAdd(&dH[key], 1);
        }
    }
    __syncthreads();

    int k0 = dH[2 * t], k1 = dH[2 * t + 1];
    int tot = k0 + k1;
    ts[t] = tot;
    __syncthreads();
    for (int off = 1; off < 256; off <<= 1) {
        int v = (t >= off) ? ts[t - off] : 0;
        __syncthreads();
        ts[t] += v;
        __syncthreads();
    }
    int tb = ts[t] - tot;
    cur[2 * t]     = tb;
    cur[2 * t + 1] = tb + k0;
    __syncthreads();

    if (t <= NPB) nb[t] = (t < NPB) ? cur[t << 2] : n;
    __syncthreads();

#pragma unroll
    for (int k = 0; k < RPT; ++k) {
        if (mrx[k] != -1) {
            int key = (((mrx[k] >> 19) & 0x7F) << 2) | ((mrx[k] >> 17) & 3);
            int pos = atomicAdd(&cur[key], 1);
            tmp[(size_t)b * BCAP + pos] = make_int2(mrx[k], mry[k]);
        }
    }

    if (t < NPB) {
        int node = b * NPB + t;
        if (node < N_NODES) {
            offs[node] = b * BCAP + nb[t];
            cnts[node] = nb[t + 1] - nb[t];
        }
    }
}

// ---------------------------------------------------------------------------
// gatherb (proven body, ~102 us): wave per node; 4 records per round, each
// row read by one 16-lane quarter as uint4. Rotation at load time via packed
// bf16x2 word shift; 8 named scalar accumulators (no aggregates, no scratch).
// ---------------------------------------------------------------------------
#define GB_ACCUM(RX, RY)                                                       \
    {                                                                          \
        const uint4* rowp = (const uint4*)(xb + (size_t)((RX) & 0x1FFFF) * D); \
        uint4 v = rowp[l16];                                                   \
        int sh = ((RX) >> 17) & 3;                                             \
        float sc = __int_as_float(RY);                                         \
        unsigned int pw = (unsigned int)__shfl((int)v.w, prevq);               \
        unsigned int s1x = ALIGN16(v.x, pw);                                   \
        unsigned int s1y = ALIGN16(v.y, v.x);                                  \
        unsigned int s1z = ALIGN16(v.z, v.y);                                  \
        unsigned int s1w = ALIGN16(v.w, v.z);                                  \
        unsigned int u0 = (sh == 0) ? v.x : (sh == 1) ? s1x : pw;              \
        unsigned int u1 = (sh == 0) ? v.y : (sh == 1) ? s1y : v.x;             \
        unsigned int u2 = (sh == 0) ? v.z : (sh == 1) ? s1z : v.y;             \
        unsigned int u3 = (sh == 0) ? v.w : (sh == 1) ? s1w : v.z;             \
        acc0 += sc * __uint_as_float(u0 << 16);                                \
        acc1 += sc * __uint_as_float(u0 & 0xFFFF0000u);                        \
        acc2 += sc * __uint_as_float(u1 << 16);                                \
        acc3 += sc * __uint_as_float(u1 & 0xFFFF0000u);                        \
        acc4 += sc * __uint_as_float(u2 << 16);                                \
        acc5 += sc * __uint_as_float(u2 & 0xFFFF0000u);                        \
        acc6 += sc * __uint_as_float(u3 << 16);                                \
        acc7 += sc * __uint_as_float(u3 & 0xFFFF0000u);                        \
    }

__global__ __launch_bounds__(256) void gatherb_kernel(
        const float* __restrict__ x, const ushort* __restrict__ xb,
        const int* __restrict__ offs, const int* __restrict__ cnts,
        const int2* __restrict__ recs,
        const float* __restrict__ z0, const float* __restrict__ z1,
        const float* __restrict__ z2, const float* __restrict__ z3,
        float* __restrict__ out) {
    int wid  = (blockIdx.x * blockDim.x + threadIdx.x) >> 6;
    int lane = threadIdx.x & 63;
    if (wid >= N_NODES) return;

    float r0, r1, r2, r3;
    load_r(z0, z1, z2, z3, r0, r1, r2, r3);

    int qt    = lane >> 4;                    // record slot within 4-group
    int l16   = lane & 15;                    // 16 lanes x uint4 = 256 B row
    int prevq = (qt << 4) | ((l16 + 15) & 15);

    int beg   = offs[wid];
    int count = cnts[wid];
    int cnt64 = (count < 64) ? count : 64;

    int mrx = 0, mry = 0;                     // pad: row 0, scale 0
    if (lane < cnt64) { int2 rec = recs[beg + lane]; mrx = rec.x; mry = rec.y; }

    float acc0 = 0.f, acc1 = 0.f, acc2 = 0.f, acc3 = 0.f;
    float acc4 = 0.f, acc5 = 0.f, acc6 = 0.f, acc7 = 0.f;

    for (int j = 0; j < cnt64; j += 4) {
        int srcl = j + qt;                    // <= 63 always (j <= 60)
        int rx = __shfl(mrx, srcl);
        int ry = __shfl(mry, srcl);
        GB_ACCUM(rx, ry)
    }
    for (int q = 64; q < count; q += 4) {     // rare high-degree tail
        int qq = q + qt;
        int rx = 0, ry = 0;
        if (qq < count) { int2 rec = recs[beg + qq]; rx = rec.x; ry = rec.y; }
        GB_ACCUM(rx, ry)
    }

    acc0 += __shfl_xor(acc0, 16); acc0 += __shfl_xor(acc0, 32);
    acc1 += __shfl_xor(acc1, 16); acc1 += __shfl_xor(acc1, 32);
    acc2 += __shfl_xor(acc2, 16); acc2 += __shfl_xor(acc2, 32);
    acc3 += __shfl_xor(acc3, 16); acc3 += __shfl_xor(acc3, 32);
    acc4 += __shfl_xor(acc4, 16); acc4 += __shfl_xor(acc4, 32);
    acc5 += __shfl_xor(acc5, 16); acc5 += __shfl_xor(acc5, 32);
    acc6 += __shfl_xor(acc6, 16); acc6 += __shfl_xor(acc6, 32);
    acc7 += __shfl_xor(acc7, 16); acc7 += __shfl_xor(acc7, 32);

    if (lane < 16) {
        const float4* xr = (const float4*)(x + (size_t)wid * D);
        float4 xlo = xr[2 * l16];
        float4 xhi = xr[2 * l16 + 1];
        float4 olo, ohi;
        olo.x = r0 * xlo.x + acc0;
        olo.y = r0 * xlo.y + acc1;
        olo.z = r0 * xlo.z + acc2;
        olo.w = r0 * xlo.w + acc3;
        ohi.x = r0 * xhi.x + acc4;
        ohi.y = r0 * xhi.y + acc5;
        ohi.z = r0 * xhi.z + acc6;
        ohi.w = r0 * xhi.w + acc7;
        float4* op = (float4*)(out + (size_t)wid * D);
        op[2 * l16]     = olo;
        op[2 * l16 + 1] = ohi;
    }
}

// overflow cleanup: wave per record, atomic add (expected ~0 records)
__global__ void ovf_kernel(const float* __restrict__ x,
                           const int* __restrict__ ovf_count,
                           const int4* __restrict__ ovf,
                           float* __restrict__ out) {
    int total_waves = (gridDim.x * blockDim.x) >> 6;
    int gw   = (blockIdx.x * blockDim.x + threadIdx.x) >> 6;
    int lane = threadIdx.x & 63;
    int n = *ovf_count;
    if (n > OVF_CAP) n = OVF_CAP;
    for (int r = gw; r < n; r += total_waves) {
        int4 rec = ovf[r];
        int src = rec.x;
        int dst = rec.y & 0x1FFFF;
        int sh  = (rec.y >> 17) & 3;
        float sc = __int_as_float(rec.z);
        const float* xr = x + (size_t)dst * D;
        float* orow = out + (size_t)src * D;
        int c0 = 2 * lane, c1 = 2 * lane + 1;
        atomicAdd(&orow[c0], sc * xr[(c0 - sh) & 127]);
        atomicAdd(&orow[c1], sc * xr[(c1 - sh) & 127]);
    }
}

// ===========================================================================
// MID TIER fallback (exact-CSR path, fp32 gather), if ws too small.
// ===========================================================================
#define SCAN_BLOCKS ((N_NODES + 255) / 256)   // 391
#define WS_COUNTS   0
#define WS_OFFSETS  400000
#define WS_CURSORS  800008
#define WS_BSUM     1200008
#define WS_BPRE     1201576
#define WS_RECS     1203144
#define WS_NEEDED_MID (WS_RECS + (size_t)TOT_EDGES * 8)

__global__ void hist_kernel(const int* __restrict__ ei1, const int* __restrict__ ei2,
                            const int* __restrict__ ei3, int* __restrict__ counts) {
    int e = blockIdx.x * blockDim.x + threadIdx.x;
    if (e >= TOT_EDGES) return;
    int set = e / N_EDGES;
    int idx = e - set * N_EDGES;
    const int* ei = (set == 0) ? ei1 : (set == 1) ? ei2 : ei3;
    atomicAdd(&counts[ei[idx]], 1);
}

__global__ void scan1_kernel(const int* __restrict__ counts,
                             int* __restrict__ offsets, int* __restrict__ bsum) {
    __shared__ int s[256];
    int t = threadIdx.x;
    int i = blockIdx.x * 256 + t;
    int v = (i < N_NODES) ? counts[i] : 0;
    s[t] = v;
    __syncthreads();
    for (int off = 1; off < 256; off <<= 1) {
        int u = (t >= off) ? s[t - off] : 0;
        __syncthreads();
        s[t] += u;
        __syncthreads();
    }
    if (i < N_NODES) offsets[i] = s[t] - v;
    if (t == 255) bsum[blockIdx.x] = s[255];
}

__global__ void scan2_kernel(const int* __restrict__ bsum, int* __restrict__ bpre) {
    __shared__ int s[512];
    int t = threadIdx.x;
    int v = (t < SCAN_BLOCKS) ? bsum[t] : 0;
    s[t] = v;
    __syncthreads();
    for (int off = 1; off < 512; off <<= 1) {
        int u = (t >= off) ? s[t - off] : 0;
        __syncthreads();
        s[t] += u;
        __syncthreads();
    }
    if (t < SCAN_BLOCKS) bpre[t] = s[t] - v;
}

__global__ void scan3_kernel(int* __restrict__ offsets, const int* __restrict__ bpre,
                             int* __restrict__ cursors) {
    int i = blockIdx.x * 256 + threadIdx.x;
    if (i < N_NODES) {
        int v = offsets[i] + bpre[blockIdx.x];
        offsets[i] = v;
        cursors[i] = v;
    }
    if (i == 0) offsets[N_NODES] = TOT_EDGES;
}

__global__ void fill_kernel(const int* __restrict__ ei1, const float* __restrict__ w1,
                            const int* __restrict__ ei2, const float* __restrict__ w2,
                            const int* __restrict__ ei3, const float* __restrict__ w3,
                            const float* __restrict__ z0, const float* __restrict__ z1,
                            const float* __restrict__ z2, const float* __restrict__ z3,
                            int* __restrict__ cursors, int2* __restrict__ recs) {
    int e = blockIdx.x * blockDim.x + threadIdx.x;
    if (e >= TOT_EDGES) return;
    int set = e / N_EDGES;
    int idx = e - set * N_EDGES;
    const int* ei;  const float* w;
    if      (set == 0) { ei = ei1; w = w1; }
    else if (set == 1) { ei = ei2; w = w2; }
    else               { ei = ei3; w = w3; }
    float r0, r1, r2, r3;
    load_r(z0, z1, z2, z3, r0, r1, r2, r3);
    float rk = (set == 0) ? r1 : (set == 1) ? r2 : r3;
    int src = ei[idx];
    int dst = ei[N_EDGES + idx];
    float scale = rk * w[idx];
    int pos = atomicAdd(&cursors[src], 1);
    recs[pos] = make_int2(dst | (set << 17), __float_as_int(scale));
}

__global__ void gatherd_kernel(const float* __restrict__ x,
                               const int* __restrict__ offsets,
                               const int2* __restrict__ recs,
                               const float* __restrict__ z0, const float* __restrict__ z1,
                               const float* __restrict__ z2, const float* __restrict__ z3,
                               float* __restrict__ out) {
    int wid  = (blockIdx.x * blockDim.x + threadIdx.x) >> 6;
    int lane = threadIdx.x & 63;
    if (wid >= N_NODES) return;
    float r0, r1, r2, r3;
    load_r(z0, z1, z2, z3, r0, r1, r2, r3);
    float2 xv = ((const float2*)(x + (size_t)wid * D))[lane];
    int beg = offsets[wid];
    int end = offsets[wid + 1];
    float2 a0 = {0.f, 0.f}, a1 = {0.f, 0.f}, a2 = {0.f, 0.f};
    for (int j = beg; j < end; ++j) {
        int2 rec = recs[j];
        float2 v = ((const float2*)(x + (size_t)(rec.x & 0x1FFFF) * D))[lane];
        int sh = (rec.x >> 17) & 3;
        float sc = __int_as_float(rec.y);
        if      (sh == 0) { a0.x += sc * v.x; a0.y += sc * v.y; }
        else if (sh == 1) { a1.x += sc * v.x; a1.y += sc * v.y; }
        else               { a2.x += sc * v.x; a2.y += sc * v.y; }
    }
    int prev = (lane + 63) & 63;
    float r1y = __shfl(a1.y, prev);
    float r2x = __shfl(a2.x, prev);
    float r2y = __shfl(a2.y, prev);
    float2 o;
    o.x = r0 * xv.x + a0.x + r1y  + r2x;
    o.y = r0 * xv.y + a0.y + a1.x + r2y;
    ((float2*)(out + (size_t)wid * D))[lane] = o;
}

extern "C" void kernel_launch(void* const* d_in, const int* in_sizes, int n_in,
                              void* d_out, int out_size, void* d_ws, size_t ws_size,
                              hipStream_t stream) {
    const float* x   = (const float*)d_in[0];
    const int*   ei1 = (const int*)  d_in[1];
    const float* w1  = (const float*)d_in[2];
    const int*   ei2 = (const int*)  d_in[3];
    const float* w2  = (const float*)d_in[4];
    const int*   ei3 = (const int*)  d_in[5];
    const float* w3  = (const float*)d_in[6];
    const float* z0  = (const float*)d_in[7];
    const float* z1  = (const float*)d_in[8];
    const float* z2  = (const float*)d_in[9];
    const float* z3  = (const float*)d_in[10];
    float* out = (float*)d_out;
    char* wsc = (char*)d_ws;

    if (ws_size >= WS_TOTAL_FAST) {
        int*    ovf_count = (int*)   (wsc + WS_OVFCNT);
        int*    bcur      = (int*)   (wsc + WS_BCUR);
        int4*   ovf       = (int4*)  (wsc + WS_OVF);
        int2*   tmp       = (int2*)  (wsc + WS_TMP);
        int*    offs      = (int*)   (wsc + WS_OFFS);
        int*    cnts      = (int*)   (wsc + WS_CNTS);
        ushort* xb        = (ushort*)(wsc + WS_XB);

        hipMemsetAsync(wsc, 0, WS_OVF, stream);   // ovf_count + bucket cursors
        prep_kernel<<<BLKA + CAST_BLOCKS, 256, 0, stream>>>(
            x, xb, ei1, w1, ei2, w2, ei3, w3, z0, z1, z2, z3,
            bcur, ovf_count, ovf, tmp);
        binB_kernel<<<NB, 256, 0, stream>>>(bcur, tmp, offs, cnts);
        gatherb_kernel<<<(N_NODES * 64 + 255) / 256, 256, 0, stream>>>(
            x, xb, offs, cnts, tmp, z0, z1, z2, z3, out);
        ovf_kernel<<<128, 256, 0, stream>>>(x, ovf_count, ovf, out);
    } else {
        int*  counts  = (int*) (wsc + WS_COUNTS);
        int*  offsets = (int*) (wsc + WS_OFFSETS);
        int*  cursors = (int*) (wsc + WS_CURSORS);
        int*  bsum    = (int*) (wsc + WS_BSUM);
        int*  bpre    = (int*) (wsc + WS_BPRE);
        int2* recs    = (int2*)(wsc + WS_RECS);

        hipMemsetAsync(counts, 0, N_NODES * sizeof(int), stream);
        hist_kernel<<<TOT_EDGES / 256, 256, 0, stream>>>(ei1, ei2, ei3, counts);
        scan1_kernel<<<SCAN_BLOCKS, 256, 0, stream>>>(counts, offsets, bsum);
        scan2_kernel<<<1, 512, 0, stream>>>(bsum, bpre);
        scan3_kernel<<<SCAN_BLOCKS, 256, 0, stream>>>(offsets, bpre, cursors);
        fill_kernel<<<TOT_EDGES / 256, 256, 0, stream>>>(ei1, w1, ei2, w2, ei3, w3,
                                                         z0, z1, z2, z3, cursors, recs);
        gatherd_kernel<<<(N_NODES * 64 + 255) / 256, 256, 0, stream>>>(x, offsets, recs,
                                                                       z0, z1, z2, z3, out);
    }
}